// Round 8
// baseline (234.704 us; speedup 1.0000x reference)
//
#include <hip/hip_runtime.h>
#include <math.h>

#define D_MODEL 512
#define NSTATE  64
#define LSEQ    2048
#define L2X     4096
#define NBATCH  8
#define NTC     512     // conv threads
#define NTA     1024    // khat threads

__device__ __forceinline__ float2 cmulf(float2 a, float2 b) {
    return make_float2(a.x * b.x - a.y * b.y, a.x * b.y + a.y * b.x);
}
__device__ __forceinline__ float2 cmulc(float2 a, float2 w) {   // a * conj(w)
    return make_float2(a.x * w.x + a.y * w.y, a.y * w.x - a.x * w.y);
}
__device__ __forceinline__ float2 cadd(float2 a, float2 b) { return make_float2(a.x + b.x, a.y + b.y); }
__device__ __forceinline__ float2 csub(float2 a, float2 b) { return make_float2(a.x - b.x, a.y - b.y); }
__device__ __forceinline__ float rcpf(float x) { return __builtin_amdgcn_rcpf(x); }
__device__ __forceinline__ float2 cdiv_fast(float2 a, float2 b) {
    float inv = rcpf(b.x * b.x + b.y * b.y);
    return make_float2((a.x * b.x + a.y * b.y) * inv, (a.y * b.x - a.x * b.y) * inv);
}
__device__ __forceinline__ int finitef(float v) {
    return (v == v) && (v < 3.0e38f) && (v > -3.0e38f);
}
__device__ __forceinline__ int brev11(int x) { return (int)(__brev((unsigned)x) >> 21); }
__device__ __forceinline__ int digrev12(int x) {
    unsigned r = __brev((unsigned)x) >> 20;
    return (int)(((r & 0x555u) << 1) | ((r >> 1) & 0x555u));
}

// quarter table tw[k]=exp(-2*pi*i*k/4096), k in [0,1024); full circle via exact rotations
__device__ __forceinline__ float2 twget4(const float2* tw, int k) {
    float2 w = tw[k & 1023];
    if (k & 1024) w = make_float2(w.y, -w.x);    // * -i
    if (k & 2048) w = make_float2(-w.x, -w.y);   // * -1
    return w;
}
template<int TPB>
__device__ __forceinline__ void build_tw(float2* tw) {
    for (int k = threadIdx.x; k < 1024; k += TPB) {
        float ang = -1.5339807878856412e-3f * (float)k;   // -2*pi/4096
        float s, c;
        sincosf(ang, &s, &c);
        tw[k] = make_float2(c, s);
    }
}

// complex input unmarshal (verified rounds 4-7)
__device__ __forceinline__ float2 ldc(const float* f, int n, int mode) {
    if (mode == 0) return make_float2(f[n], 0.0f);
    if (mode == 1) return make_float2(f[n], f[64 + n]);
    return make_float2(f[2 * n], f[2 * n + 1]);
}

// In-place radix-2 DIF (natural -> bit-reversed), 2048-pt step in khat only.
template<int TPB>
__device__ void dif_fft2(float2* buf, const float2* tw, int log2N) {
    const int tid = threadIdx.x;
    const int halfN = 1 << (log2N - 1);
    for (int lm = log2N - 1; lm >= 0; lm--) {
        const int m = 1 << lm;
        __syncthreads();
        for (int t = tid; t < halfN; t += TPB) {
            int j = t & (m - 1);
            int i0 = ((t - j) << 1) + j;
            int i1 = i0 + m;
            float2 a = buf[i0], b = buf[i1];
            buf[i0] = cadd(a, b);
            buf[i1] = cmulf(csub(a, b), twget4(tw, j << (11 - lm)));
        }
    }
    __syncthreads();
}

// Radix-4 DIF stages h=256..1 (stage h=1024 done in registers by the caller).
// natural -> digit-reversed, unnormalized forward.
template<int TPB>
__device__ void dif_fft4_rest(float2* buf, const float2* tw) {
    const int tid = threadIdx.x;
    int f = 4;
    for (int h = 256; h >= 1; h >>= 2, f <<= 2) {
        __syncthreads();
        for (int t = tid; t < 1024; t += TPB) {
            int j = t & (h - 1);
            int i0 = ((t - j) << 2) + j;
            float2 a = buf[i0], b = buf[i0 + h], c = buf[i0 + 2 * h], d = buf[i0 + 3 * h];
            float2 t0 = cadd(a, c), t1 = csub(a, c);
            float2 t2 = cadd(b, d), t3 = csub(b, d);
            float2 e1 = make_float2(t1.x + t3.y, t1.y - t3.x);   // t1 - i*t3
            float2 e3 = make_float2(t1.x - t3.y, t1.y + t3.x);   // t1 + i*t3
            int k = j * f;
            buf[i0]         = cadd(t0, t2);
            buf[i0 + h]     = cmulf(e1, twget4(tw, k));
            buf[i0 + 2 * h] = cmulf(csub(t0, t2), twget4(tw, 2 * k));
            buf[i0 + 3 * h] = cmulf(e3, twget4(tw, 3 * k));
        }
    }
    __syncthreads();
}

// In-place radix-4 DIT inverse, N=4096: digit-reversed -> natural, unnormalized.
template<int TPB>
__device__ void dit_ifft4(float2* buf, const float2* tw) {
    const int tid = threadIdx.x;
    int f = 1024;
    for (int h = 1; h <= 1024; h <<= 2, f >>= 2) {
        __syncthreads();
        for (int t = tid; t < 1024; t += TPB) {
            int j = t & (h - 1);
            int i0 = ((t - j) << 2) + j;
            int k = j * f;
            float2 a = buf[i0];
            float2 b = cmulc(buf[i0 + h],     twget4(tw, k));
            float2 c = cmulc(buf[i0 + 2 * h], twget4(tw, 2 * k));
            float2 d = cmulc(buf[i0 + 3 * h], twget4(tw, 3 * k));
            float2 t0 = cadd(a, c), t1 = csub(a, c);
            float2 t2 = cadd(b, d), t3 = csub(b, d);
            buf[i0]         = cadd(t0, t2);
            buf[i0 + h]     = make_float2(t1.x - t3.y, t1.y + t3.x);  // t1 + i*t3
            buf[i0 + 2 * h] = csub(t0, t2);
            buf[i0 + 3 * h] = make_float2(t1.x + t3.y, t1.y - t3.x);  // t1 - i*t3
        }
    }
    __syncthreads();
}

// ---------------- Kernel A: Khat[d][pos] = (1/(2048*4096)) * DIF4(pad(K_d)), digitrev order ----
__global__ __launch_bounds__(NTA) void s4_khat_kernel(
    const float* __restrict__ Bmat, const float* __restrict__ Ct,
    const float* __restrict__ log_step,
    const float* __restrict__ pf, const float* __restrict__ qf,
    const float* __restrict__ lf,
    float2* __restrict__ Khat, int size_hint)
{
    __shared__ float2 tw[1024];
    __shared__ float2 buf[L2X];
    const int d = blockIdx.x;
    const int tid = threadIdx.x;

    build_tw<NTA>(tw);

    // layout detection (verified rounds 4-7)
    int mode;
    if (size_hint >= 128) {
        mode = (fabsf(lf[1] + 0.5f) < 0.05f) ? 1 : 2;
    } else {
        float s1 = 0.0f, s2 = 0.0f;
        bool ok = true;
        for (int n = 0; n < 64; n++) {
            float v = lf[64 + n];
            if (!finitef(v)) { ok = false; break; }
            s1 += v; s2 += fabsf(v);
        }
        mode = (ok && s2 > 0.5f && s2 < 1.0e6f && fabsf(s1) < 1.0e-2f * s2) ? 1 : 0;
    }

    // stash per-d arrays in buf tail [2048, 2336)
    float2* v01  = buf + LSEQ;
    float2* v10  = buf + LSEQ + 64;
    float2* v11  = buf + LSEQ + 128;
    float2* lamS = buf + LSEQ + 192;
    float*  v00  = (float*)(buf + LSEQ + 256);

    if (tid < NSTATE) {
        int n = tid;
        float Bdn = Bmat[d * NSTATE + n];
        float Cdn = Ct[d * NSTATE + n];
        float2 pn = ldc(pf, n, mode);
        float2 qn = ldc(qf, n, mode);
        float2 qc = make_float2(qn.x, -qn.y);
        v00[n]  = Cdn * Bdn;
        v01[n]  = make_float2(Cdn * pn.x, Cdn * pn.y);
        v10[n]  = make_float2(qc.x * Bdn, qc.y * Bdn);
        v11[n]  = cmulf(qc, pn);
        lamS[n] = ldc(lf, n, mode);
    }
    const float two_over_step = 2.0f / expf(log_step[d]);
    __syncthreads();   // tw + stash visible

    // ---- Cauchy phase: n-outer, 2 l-values per thread in registers ----
    float gxr[2], gyr[2];
    float2 a00[2], a01[2], a10[2], a11[2];
    #pragma unroll
    for (int i = 0; i < 2; i++) {
        int l = tid + i * NTA;
        float2 w = twget4(tw, 2 * l);          // exp(-2*pi*i*l/2048)
        float cth = w.x, sth = -w.y;           // omega = exp(+2*pi*i*l/2048)
        float opx = 1.0f + cth, opy = sth;
        float omx = 1.0f - cth, omy = -sth;
        float invD = rcpf(opx * opx + opy * opy);
        gxr[i] = two_over_step * (omx * opx + omy * opy) * invD;
        gyr[i] = two_over_step * (omy * opx - omx * opy) * invD;
        a00[i] = make_float2(0.f, 0.f); a01[i] = make_float2(0.f, 0.f);
        a10[i] = make_float2(0.f, 0.f); a11[i] = make_float2(0.f, 0.f);
    }
    for (int n = 0; n < NSTATE; n++) {
        float2 ln = lamS[n];
        float  c0 = v00[n];
        float2 c1 = v01[n], c2 = v10[n], c3 = v11[n];
        #pragma unroll
        for (int i = 0; i < 2; i++) {
            float dx = gxr[i] - ln.x, dy = gyr[i] - ln.y;
            float ir = rcpf(dx * dx + dy * dy);
            float rx = dx * ir, ry = -dy * ir;
            a00[i].x += c0 * rx;               a00[i].y += c0 * ry;
            a01[i].x += c1.x * rx - c1.y * ry; a01[i].y += c1.x * ry + c1.y * rx;
            a10[i].x += c2.x * rx - c2.y * ry; a10[i].y += c2.x * ry + c2.y * rx;
            a11[i].x += c3.x * rx - c3.y * ry; a11[i].y += c3.x * ry + c3.y * rx;
        }
    }
    __syncthreads();
    #pragma unroll
    for (int i = 0; i < 2; i++) {
        int l = tid + i * NTA;
        float2 w = twget4(tw, 2 * l);
        float cth = w.x, sth = -w.y;
        float opx = 1.0f + cth, opy = sth;
        float invD = rcpf(opx * opx + opy * opy);
        float2 cl = make_float2(2.0f * opx * invD, -2.0f * opy * invD);
        float2 onep = make_float2(1.0f + a11[i].x, a11[i].y);
        float2 corr = cdiv_fast(cmulf(a01[i], a10[i]), onep);
        float2 ar = cmulf(cl, csub(a00[i], corr));
        if (!finitef(ar.x) || !finitef(ar.y)) ar = make_float2(0.0f, 0.0f);
        buf[l] = ar;
    }

    // K[t] = Re(DFT2048(at_roots)[brev11(t)]) / 2048 -> kr regs (t = tid, tid+1024)
    dif_fft2<NTA>(buf, tw, 11);
    float kr[2];
    const float inv2048 = 1.0f / 2048.0f;
    kr[0] = buf[brev11(tid)].x * inv2048;
    kr[1] = buf[brev11(tid + 1024)].x * inv2048;
    __syncthreads();   // all kr reads done before buf is overwritten

    // 4096-pt radix-4 DIF, stage h=1024 in registers (c=d=0, a=kr[0], b=kr[1] real):
    {
        int j = tid;                      // j in [0,1024)
        float a = kr[0], b = kr[1];
        float2 w1 = twget4(tw, j);
        float2 w2 = twget4(tw, 2 * j);
        float2 w3 = twget4(tw, 3 * j);
        buf[j]        = make_float2(a + b, 0.0f);
        buf[j + 1024] = make_float2(a * w1.x + b * w1.y, a * w1.y - b * w1.x);  // (a-ib)*w1
        float amb = a - b;
        buf[j + 2048] = make_float2(amb * w2.x, amb * w2.y);
        buf[j + 3072] = make_float2(a * w3.x - b * w3.y, a * w3.y + b * w3.x);  // (a+ib)*w3
    }
    dif_fft4_rest<NTA>(buf, tw);   // digit-reversed order (conv matches)

    const float inv4096 = 1.0f / 4096.0f;   // fold inverse-transform scale in
    for (int k = tid; k < L2X; k += NTA) {
        float2 v = buf[k];
        float vx = v.x * inv4096, vy = v.y * inv4096;
        if (!finitef(vx)) vx = 0.0f;
        if (!finitef(vy)) vy = 0.0f;
        Khat[(size_t)d * L2X + k] = make_float2(vx, vy);
    }
}

// ---------------- Kernel B: two-for-one causal conv, channels (2d0, 2d0+1) per block --------
__global__ __launch_bounds__(NTC) void conv_kernel(
    const float* __restrict__ u, const float2* __restrict__ Khat,
    const float* __restrict__ Dvec, float* __restrict__ out)
{
    __shared__ float2 tw[1024];
    __shared__ float2 buf[L2X];
    const int blk = blockIdx.x;
    const int d0 = blk >> 3;        // 8 consecutive blocks share d0 -> Khat L2 reuse
    const int b  = blk & 7;
    const int tid = threadIdx.x;

    build_tw<NTC>(tw);

    float2 ureg[4];
    #pragma unroll
    for (int i = 0; i < 4; i++) {
        int t = tid + i * NTC;
        ureg[i] = *(const float2*)(u + ((size_t)b * LSEQ + t) * D_MODEL + 2 * d0);
    }
    __syncthreads();   // tw visible before register-stage twiddle reads

    // 4096-pt radix-4 DIF, stage h=1024 in registers (top half zero):
    // quadruple j=tid:     a=z(tid),     b=z(tid+1024) = (ureg[0], ureg[2])
    // quadruple j=tid+512: a=z(tid+512), b=z(tid+1536) = (ureg[1], ureg[3])
    #pragma unroll
    for (int qq = 0; qq < 2; qq++) {
        int j = tid + qq * NTC;
        float2 a = ureg[qq], bb = ureg[qq + 2];
        float2 e1 = make_float2(a.x + bb.y, a.y - bb.x);   // a - i*b
        float2 e3 = make_float2(a.x - bb.y, a.y + bb.x);   // a + i*b
        buf[j]        = cadd(a, bb);
        buf[j + 1024] = cmulf(e1, twget4(tw, j));
        buf[j + 2048] = cmulf(csub(a, bb), twget4(tw, 2 * j));
        buf[j + 3072] = cmulf(e3, twget4(tw, 3 * j));
    }
    dif_fft4_rest<NTC>(buf, tw);   // Z, digit-reversed positions

    // two-for-one separation + pointwise multiply in digit-reversed domain.
    // K real => Khat[partner] = conj(Khat[p]); only coalesced K reads needed.
    const float2* K0 = Khat + (size_t)(2 * d0) * L2X;
    const float2* K1 = K0 + L2X;
    for (int t0 = tid; t0 < L2X; t0 += NTC) {
        int fr = digrev12(t0);
        int jm = digrev12((L2X - fr) & (L2X - 1));
        if (t0 > jm) continue;
        float2 Zk = buf[t0], Zm = buf[jm];
        float2 U0 = make_float2(0.5f * (Zk.x + Zm.x), 0.5f * (Zk.y - Zm.y));
        float2 U1 = make_float2(0.5f * (Zk.y + Zm.y), 0.5f * (Zm.x - Zk.x));
        float2 Y0 = cmulf(U0, K0[t0]);
        float2 Y1 = cmulf(U1, K1[t0]);
        buf[t0] = make_float2(Y0.x - Y1.y, Y0.y + Y1.x);   // V(f)    = Y0 + i*Y1
        buf[jm] = make_float2(Y0.x + Y1.y, Y1.x - Y0.y);   // V(N-f) = conj(Y0 - i*Y1)
    }
    dit_ifft4<NTC>(buf, tw);  // natural order; y0 = Re, y1 = Im (scale folded into Khat)

    const float dv0 = Dvec[2 * d0];
    const float dv1 = Dvec[2 * d0 + 1];
    #pragma unroll
    for (int i = 0; i < 4; i++) {
        int t = tid + i * NTC;
        float2 y = buf[t];
        float o0 = y.x + dv0 * ureg[i].x;
        float o1 = y.y + dv1 * ureg[i].y;
        if (!finitef(o0)) o0 = 4.0e5f;
        if (!finitef(o1)) o1 = 4.0e5f;
        *(float2*)(out + ((size_t)b * LSEQ + t) * D_MODEL + 2 * d0) = make_float2(o0, o1);
    }
}

extern "C" void kernel_launch(void* const* d_in, const int* in_sizes, int n_in,
                              void* d_out, int out_size, void* d_ws, size_t ws_size,
                              hipStream_t stream) {
    (void)n_in; (void)out_size; (void)ws_size;
    const float* u        = (const float*)d_in[0];
    const float* Bmat     = (const float*)d_in[1];
    const float* Ct       = (const float*)d_in[2];
    const float* Dvec     = (const float*)d_in[3];
    const float* log_step = (const float*)d_in[4];
    const float* pf       = (const float*)d_in[5];
    const float* qf       = (const float*)d_in[6];
    const float* lf       = (const float*)d_in[7];
    float* out = (float*)d_out;

    int size_hint = in_sizes[5];

    // workspace: Khat (D_MODEL x 4096 complex64 = 16 MiB), digit-reversed-4096 order
    float2* Khat = (float2*)d_ws;

    s4_khat_kernel<<<D_MODEL, NTA, 0, stream>>>(Bmat, Ct, log_step, pf, qf, lf, Khat, size_hint);
    conv_kernel<<<NBATCH * (D_MODEL / 2), NTC, 0, stream>>>(u, Khat, Dvec, out);
}

// Round 9
// 230.678 us; speedup vs baseline: 1.0175x; 1.0175x over previous
//
#include <hip/hip_runtime.h>
#include <math.h>

#define D_MODEL 512
#define NSTATE  64
#define LSEQ    2048
#define L2X     4096
#define NBATCH  8
#define NTC     512     // conv threads
#define NTF     512     // kfft threads
#define NTCA    256     // cauchy threads

__device__ __forceinline__ float2 cmulf(float2 a, float2 b) {
    return make_float2(a.x * b.x - a.y * b.y, a.x * b.y + a.y * b.x);
}
__device__ __forceinline__ float2 cmulc(float2 a, float2 w) {   // a * conj(w)
    return make_float2(a.x * w.x + a.y * w.y, a.y * w.x - a.x * w.y);
}
__device__ __forceinline__ float2 cadd(float2 a, float2 b) { return make_float2(a.x + b.x, a.y + b.y); }
__device__ __forceinline__ float2 csub(float2 a, float2 b) { return make_float2(a.x - b.x, a.y - b.y); }
__device__ __forceinline__ float rcpf(float x) { return __builtin_amdgcn_rcpf(x); }
__device__ __forceinline__ float2 cdiv_fast(float2 a, float2 b) {
    float inv = rcpf(b.x * b.x + b.y * b.y);
    return make_float2((a.x * b.x + a.y * b.y) * inv, (a.y * b.x - a.x * b.y) * inv);
}
__device__ __forceinline__ int finitef(float v) {
    return (v == v) && (v < 3.0e38f) && (v > -3.0e38f);
}
__device__ __forceinline__ int brev11(int x) { return (int)(__brev((unsigned)x) >> 21); }
__device__ __forceinline__ int digrev12(int x) {
    unsigned r = __brev((unsigned)x) >> 20;
    return (int)(((r & 0x555u) << 1) | ((r >> 1) & 0x555u));
}

// quarter table tw[k]=exp(-2*pi*i*k/4096), k in [0,1024); full circle via exact rotations
__device__ __forceinline__ float2 twget4(const float2* tw, int k) {
    float2 w = tw[k & 1023];
    if (k & 1024) w = make_float2(w.y, -w.x);    // * -i
    if (k & 2048) w = make_float2(-w.x, -w.y);   // * -1
    return w;
}
template<int TPB>
__device__ __forceinline__ void build_tw(float2* tw) {
    for (int k = threadIdx.x; k < 1024; k += TPB) {
        float ang = -1.5339807878856412e-3f * (float)k;   // -2*pi/4096
        float s, c;
        sincosf(ang, &s, &c);
        tw[k] = make_float2(c, s);
    }
}

// complex input unmarshal (verified rounds 4-8)
__device__ __forceinline__ float2 ldc(const float* f, int n, int mode) {
    if (mode == 0) return make_float2(f[n], 0.0f);
    if (mode == 1) return make_float2(f[n], f[64 + n]);
    return make_float2(f[2 * n], f[2 * n + 1]);
}

// In-place radix-2 DIF (natural -> bit-reversed), 2048-pt step in kfft only.
template<int TPB>
__device__ void dif_fft2(float2* buf, const float2* tw, int log2N) {
    const int tid = threadIdx.x;
    const int halfN = 1 << (log2N - 1);
    for (int lm = log2N - 1; lm >= 0; lm--) {
        const int m = 1 << lm;
        __syncthreads();
        for (int t = tid; t < halfN; t += TPB) {
            int j = t & (m - 1);
            int i0 = ((t - j) << 1) + j;
            int i1 = i0 + m;
            float2 a = buf[i0], b = buf[i1];
            buf[i0] = cadd(a, b);
            buf[i1] = cmulf(csub(a, b), twget4(tw, j << (11 - lm)));
        }
    }
    __syncthreads();
}

// Radix-4 DIF stages h=256..1 (stage h=1024 done in registers by the caller).
template<int TPB>
__device__ void dif_fft4_rest(float2* buf, const float2* tw) {
    const int tid = threadIdx.x;
    int f = 4;
    for (int h = 256; h >= 1; h >>= 2, f <<= 2) {
        __syncthreads();
        for (int t = tid; t < 1024; t += TPB) {
            int j = t & (h - 1);
            int i0 = ((t - j) << 2) + j;
            float2 a = buf[i0], b = buf[i0 + h], c = buf[i0 + 2 * h], d = buf[i0 + 3 * h];
            float2 t0 = cadd(a, c), t1 = csub(a, c);
            float2 t2 = cadd(b, d), t3 = csub(b, d);
            float2 e1 = make_float2(t1.x + t3.y, t1.y - t3.x);   // t1 - i*t3
            float2 e3 = make_float2(t1.x - t3.y, t1.y + t3.x);   // t1 + i*t3
            int k = j * f;
            buf[i0]         = cadd(t0, t2);
            buf[i0 + h]     = cmulf(e1, twget4(tw, k));
            buf[i0 + 2 * h] = cmulf(csub(t0, t2), twget4(tw, 2 * k));
            buf[i0 + 3 * h] = cmulf(e3, twget4(tw, 3 * k));
        }
    }
    __syncthreads();
}

// In-place radix-4 DIT inverse, N=4096: digit-reversed -> natural, unnormalized.
template<int TPB>
__device__ void dit_ifft4(float2* buf, const float2* tw) {
    const int tid = threadIdx.x;
    int f = 1024;
    for (int h = 1; h <= 1024; h <<= 2, f >>= 2) {
        __syncthreads();
        for (int t = tid; t < 1024; t += TPB) {
            int j = t & (h - 1);
            int i0 = ((t - j) << 2) + j;
            int k = j * f;
            float2 a = buf[i0];
            float2 b = cmulc(buf[i0 + h],     twget4(tw, k));
            float2 c = cmulc(buf[i0 + 2 * h], twget4(tw, 2 * k));
            float2 d = cmulc(buf[i0 + 3 * h], twget4(tw, 3 * k));
            float2 t0 = cadd(a, c), t1 = csub(a, c);
            float2 t2 = cadd(b, d), t3 = csub(b, d);
            buf[i0]         = cadd(t0, t2);
            buf[i0 + h]     = make_float2(t1.x - t3.y, t1.y + t3.x);  // t1 + i*t3
            buf[i0 + 2 * h] = csub(t0, t2);
            buf[i0 + 3 * h] = make_float2(t1.x + t3.y, t1.y - t3.x);  // t1 - i*t3
        }
    }
    __syncthreads();
}

// ---------------- Kernel P: unmarshal p/q/lam once -> d-independent table (2 KB) ----------
// tab[2n]   = {lam.x, lam.y, p.x, p.y}
// tab[2n+1] = {qc.x, qc.y, v11.x, v11.y}   (qc = conj(q), v11 = qc*p)
__global__ void prep_kernel(const float* __restrict__ pf, const float* __restrict__ qf,
                            const float* __restrict__ lf, float4* __restrict__ tab,
                            int size_hint)
{
    const int n = threadIdx.x;   // 64 threads
    int mode;
    if (size_hint >= 128) {
        mode = (fabsf(lf[1] + 0.5f) < 0.05f) ? 1 : 2;
    } else {
        float s1 = 0.0f, s2 = 0.0f;
        bool ok = true;
        for (int k = 0; k < 64; k++) {
            float v = lf[64 + k];
            if (!finitef(v)) { ok = false; break; }
            s1 += v; s2 += fabsf(v);
        }
        mode = (ok && s2 > 0.5f && s2 < 1.0e6f && fabsf(s1) < 1.0e-2f * s2) ? 1 : 0;
    }
    float2 pn = ldc(pf, n, mode);
    float2 qn = ldc(qf, n, mode);
    float2 qc = make_float2(qn.x, -qn.y);
    float2 lamn = ldc(lf, n, mode);
    float2 v11 = cmulf(qc, pn);
    tab[2 * n]     = make_float4(lamn.x, lamn.y, pn.x, pn.y);
    tab[2 * n + 1] = make_float4(qc.x, qc.y, v11.x, v11.y);
}

// ---------------- Kernel A1: at_roots[d][l], barrier-free, scalar-operand inner loop --------
__global__ __launch_bounds__(NTCA) void cauchy_kernel(
    const float* __restrict__ Bmat, const float* __restrict__ Ct,
    const float* __restrict__ log_step, const float4* __restrict__ tab,
    float2* __restrict__ at_roots)
{
    const int blk = blockIdx.x;
    const int d = blk >> 2;                 // 4 blocks per d
    const int lbase = (blk & 3) * 512;      // each block covers 512 l, 2 per thread
    const int tid = threadIdx.x;
    const float two_over_step = 2.0f / expf(log_step[d]);   // uniform -> scalar
    const float w0 = (float)(6.283185307179586 / 2048.0);

    float gx[2], gy[2], cthv[2], sthv[2];
    float2 a00[2], a01[2], a10[2], a11[2];
    #pragma unroll
    for (int i = 0; i < 2; i++) {
        int l = lbase + tid + i * NTCA;
        float sth, cth;
        sincosf(w0 * (float)l, &sth, &cth);
        cthv[i] = cth; sthv[i] = sth;
        float opx = 1.0f + cth, opy = sth;         // 1 + omega
        float omx = 1.0f - cth, omy = -sth;        // 1 - omega
        float invD = rcpf(opx * opx + opy * opy);
        gx[i] = two_over_step * (omx * opx + omy * opy) * invD;
        gy[i] = two_over_step * (omy * opx - omx * opy) * invD;
        a00[i] = make_float2(0.f, 0.f); a01[i] = make_float2(0.f, 0.f);
        a10[i] = make_float2(0.f, 0.f); a11[i] = make_float2(0.f, 0.f);
    }

    const int dbase = d * NSTATE;
    for (int n = 0; n < NSTATE; n++) {
        float4 t0 = tab[2 * n];         // {lam.x, lam.y, p.x, p.y}   uniform -> s_load
        float4 t1 = tab[2 * n + 1];     // {qc.x, qc.y, v11.x, v11.y} uniform -> s_load
        float Bdn = Bmat[dbase + n];    // uniform -> s_load
        float Cdn = Ct[dbase + n];      // uniform -> s_load
        float c0   = Cdn * Bdn;
        float c1x = Cdn * t0.z, c1y = Cdn * t0.w;
        float c2x = t1.x * Bdn, c2y = t1.y * Bdn;
        #pragma unroll
        for (int i = 0; i < 2; i++) {
            float dx = gx[i] - t0.x, dy = gy[i] - t0.y;
            float ir = rcpf(dx * dx + dy * dy);
            float rx = dx * ir, ry = -dy * ir;
            a00[i].x += c0 * rx;              a00[i].y += c0 * ry;
            a01[i].x += c1x * rx - c1y * ry;  a01[i].y += c1x * ry + c1y * rx;
            a10[i].x += c2x * rx - c2y * ry;  a10[i].y += c2x * ry + c2y * rx;
            a11[i].x += t1.z * rx - t1.w * ry; a11[i].y += t1.z * ry + t1.w * rx;
        }
    }

    #pragma unroll
    for (int i = 0; i < 2; i++) {
        int l = lbase + tid + i * NTCA;
        float opx = 1.0f + cthv[i], opy = sthv[i];
        float invD = rcpf(opx * opx + opy * opy);
        float2 cl = make_float2(2.0f * opx * invD, -2.0f * opy * invD);
        float2 onep = make_float2(1.0f + a11[i].x, a11[i].y);
        float2 corr = cdiv_fast(cmulf(a01[i], a10[i]), onep);
        float2 ar = cmulf(cl, csub(a00[i], corr));
        if (!finitef(ar.x) || !finitef(ar.y)) ar = make_float2(0.0f, 0.0f);
        at_roots[(size_t)d * LSEQ + l] = ar;
    }
}

// ---------------- Kernel A2: Khat[d] = (1/(2048*4096)) * DIF4(pad(K_d)), digitrev order -----
__global__ __launch_bounds__(NTF) void kfft_kernel(
    const float2* __restrict__ at_roots, float2* __restrict__ Khat)
{
    __shared__ float2 tw[1024];
    __shared__ float2 buf[L2X];
    const int d = blockIdx.x;
    const int tid = threadIdx.x;

    build_tw<NTF>(tw);
    #pragma unroll
    for (int i = 0; i < 4; i++) {
        int t = tid + i * NTF;
        buf[t] = at_roots[(size_t)d * LSEQ + t];
    }
    // K[t] = Re(DFT2048(at_roots)[brev11(t)]) / 2048 -> kr regs
    dif_fft2<NTF>(buf, tw, 11);     // internal leading barrier covers loads + tw
    float kr[4];
    const float inv2048 = 1.0f / 2048.0f;
    #pragma unroll
    for (int i = 0; i < 4; i++) {
        kr[i] = buf[brev11(tid + i * NTF)].x * inv2048;
    }
    __syncthreads();   // all kr reads done before buf is overwritten

    // 4096-pt radix-4 DIF, stage h=1024 in registers (top half zero, a/b real):
    #pragma unroll
    for (int qq = 0; qq < 2; qq++) {
        int j = tid + qq * NTF;        // j in [0,1024)
        float a = kr[qq], b = kr[qq + 2];
        float2 w1 = twget4(tw, j);
        float2 w2 = twget4(tw, 2 * j);
        float2 w3 = twget4(tw, 3 * j);
        buf[j]        = make_float2(a + b, 0.0f);
        buf[j + 1024] = make_float2(a * w1.x + b * w1.y, a * w1.y - b * w1.x);  // (a-ib)*w1
        float amb = a - b;
        buf[j + 2048] = make_float2(amb * w2.x, amb * w2.y);
        buf[j + 3072] = make_float2(a * w3.x - b * w3.y, a * w3.y + b * w3.x);  // (a+ib)*w3
    }
    dif_fft4_rest<NTF>(buf, tw);   // digit-reversed order (conv matches)

    const float inv4096 = 1.0f / 4096.0f;   // fold inverse-transform scale in
    for (int k = tid; k < L2X; k += NTF) {
        float2 v = buf[k];
        float vx = v.x * inv4096, vy = v.y * inv4096;
        if (!finitef(vx)) vx = 0.0f;
        if (!finitef(vy)) vy = 0.0f;
        Khat[(size_t)d * L2X + k] = make_float2(vx, vy);
    }
}

// ---------------- Kernel B: two-for-one causal conv, channels (2d0, 2d0+1) per block --------
__global__ __launch_bounds__(NTC) void conv_kernel(
    const float* __restrict__ u, const float2* __restrict__ Khat,
    const float* __restrict__ Dvec, float* __restrict__ out)
{
    __shared__ float2 tw[1024];
    __shared__ float2 buf[L2X];
    const int blk = blockIdx.x;
    const int d0 = blk >> 3;        // 8 consecutive blocks share d0 -> Khat L2 reuse
    const int b  = blk & 7;
    const int tid = threadIdx.x;

    build_tw<NTC>(tw);

    float2 ureg[4];
    #pragma unroll
    for (int i = 0; i < 4; i++) {
        int t = tid + i * NTC;
        ureg[i] = *(const float2*)(u + ((size_t)b * LSEQ + t) * D_MODEL + 2 * d0);
    }
    __syncthreads();   // tw visible before register-stage twiddle reads

    // 4096-pt radix-4 DIF, stage h=1024 in registers (top half zero):
    #pragma unroll
    for (int qq = 0; qq < 2; qq++) {
        int j = tid + qq * NTC;
        float2 a = ureg[qq], bb = ureg[qq + 2];
        float2 e1 = make_float2(a.x + bb.y, a.y - bb.x);   // a - i*b
        float2 e3 = make_float2(a.x - bb.y, a.y + bb.x);   // a + i*b
        buf[j]        = cadd(a, bb);
        buf[j + 1024] = cmulf(e1, twget4(tw, j));
        buf[j + 2048] = cmulf(csub(a, bb), twget4(tw, 2 * j));
        buf[j + 3072] = cmulf(e3, twget4(tw, 3 * j));
    }
    dif_fft4_rest<NTC>(buf, tw);   // Z, digit-reversed positions

    // two-for-one separation + pointwise multiply in digit-reversed domain.
    // K real => Khat[partner] = conj(Khat[p]); only coalesced K reads needed.
    const float2* K0 = Khat + (size_t)(2 * d0) * L2X;
    const float2* K1 = K0 + L2X;
    for (int t0 = tid; t0 < L2X; t0 += NTC) {
        int fr = digrev12(t0);
        int jm = digrev12((L2X - fr) & (L2X - 1));
        if (t0 > jm) continue;
        float2 Zk = buf[t0], Zm = buf[jm];
        float2 U0 = make_float2(0.5f * (Zk.x + Zm.x), 0.5f * (Zk.y - Zm.y));
        float2 U1 = make_float2(0.5f * (Zk.y + Zm.y), 0.5f * (Zm.x - Zk.x));
        float2 Y0 = cmulf(U0, K0[t0]);
        float2 Y1 = cmulf(U1, K1[t0]);
        buf[t0] = make_float2(Y0.x - Y1.y, Y0.y + Y1.x);   // V(f)    = Y0 + i*Y1
        buf[jm] = make_float2(Y0.x + Y1.y, Y1.x - Y0.y);   // V(N-f) = conj(Y0 - i*Y1)
    }
    dit_ifft4<NTC>(buf, tw);  // natural order; y0 = Re, y1 = Im (scale folded into Khat)

    const float dv0 = Dvec[2 * d0];
    const float dv1 = Dvec[2 * d0 + 1];
    #pragma unroll
    for (int i = 0; i < 4; i++) {
        int t = tid + i * NTC;
        float2 y = buf[t];
        float o0 = y.x + dv0 * ureg[i].x;
        float o1 = y.y + dv1 * ureg[i].y;
        if (!finitef(o0)) o0 = 4.0e5f;
        if (!finitef(o1)) o1 = 4.0e5f;
        *(float2*)(out + ((size_t)b * LSEQ + t) * D_MODEL + 2 * d0) = make_float2(o0, o1);
    }
}

extern "C" void kernel_launch(void* const* d_in, const int* in_sizes, int n_in,
                              void* d_out, int out_size, void* d_ws, size_t ws_size,
                              hipStream_t stream) {
    (void)n_in; (void)out_size; (void)ws_size;
    const float* u        = (const float*)d_in[0];
    const float* Bmat     = (const float*)d_in[1];
    const float* Ct       = (const float*)d_in[2];
    const float* Dvec     = (const float*)d_in[3];
    const float* log_step = (const float*)d_in[4];
    const float* pf       = (const float*)d_in[5];
    const float* qf       = (const float*)d_in[6];
    const float* lf       = (const float*)d_in[7];
    float* out = (float*)d_out;

    int size_hint = in_sizes[5];

    // ws: Khat (512 x 4096 complex64 = 16 MiB), digit-reversed order
    float2* Khat = (float2*)d_ws;
    // d_out doubles as scratch before conv overwrites it:
    //   [0, 8 MiB): at_roots (512 x 2048 complex64)
    //   [24 MiB, 24 MiB + 2 KiB): prep table
    float2* at_roots = (float2*)d_out;
    float4* tab      = (float4*)((char*)d_out + 24u * 1024u * 1024u);

    prep_kernel<<<1, 64, 0, stream>>>(pf, qf, lf, tab, size_hint);
    cauchy_kernel<<<D_MODEL * 4, NTCA, 0, stream>>>(Bmat, Ct, log_step, tab, at_roots);
    kfft_kernel<<<D_MODEL, NTF, 0, stream>>>(at_roots, Khat);
    conv_kernel<<<NBATCH * (D_MODEL / 2), NTC, 0, stream>>>(u, Khat, Dvec, out);
}